// Round 1
// baseline (752.419 us; speedup 1.0000x reference)
//
#include <hip/hip_runtime.h>
#include <hip/hip_bf16.h>

// GCNConv: out = D^-1/2 (A+I) D^-1/2 (X W) + b
// N=100000, E=1600000, IN=128, OUT=64. edge_index int32, [row(E) | col(E)].
//
// Pipeline v9 — sort-free aggregation via per-bucket LDS f32 atomics:
//   0. wprep:       W fp32 [k][n] -> wbt bf16 [n][k]  (16 KB, L2-resident)
//   1. count:       1024-thr blocks, LDS histogram -> blkcnt[bucket][block]
//   2-4. scan1/2/3: multi-block exclusive scan (in-place on blkcnt) + bucket_start
//   5. place:       1024-thr blocks, pairs[pos] = row | lcol<<17 (LDS cursors)
//   6. deg:         per-bucket node histogram from pairs -> dinv
//   7. gemm:        MFMA 16x16x32 bf16; hp_bf16 = (dinv[row]*x) @ W
//   8. bucket_agg:  per-bucket acc[64][64] f32 in LDS; gather hp rows per edge,
//                   ds_add_f32 accumulate; epilogue: dinv*(acc+self)+bias.
//   (bucket_sort + per-node CSR aggregate removed: -12.8MB csr traffic,
//    -per-node wave overhead; edge work perfectly balanced.)

#define IN_CH 128
#define OUT_CH 64
#define BSHIFT 6            // 64 nodes per bucket
#define BNODES 64
#define MAX_NB 1600
#define CH_EDGES 7168       // edges per partition block (7 rounds x 1024 thr)
#define XSTR 136            // bf16 LDS row stride: 272B = 17x16B -> conflict-free b128

typedef short bf16x8 __attribute__((ext_vector_type(8)));
typedef float f32x4  __attribute__((ext_vector_type(4)));

__device__ __forceinline__ unsigned short f2b(float f) {   // RNE fp32->bf16
    unsigned int u = __float_as_uint(f);
    return (unsigned short)((u + 0x7FFFu + ((u >> 16) & 1u)) >> 16);
}

__device__ __forceinline__ void lds_add(float* p, float v) {
    __hip_atomic_fetch_add(p, v, __ATOMIC_RELAXED, __HIP_MEMORY_SCOPE_WORKGROUP);
}

// ---------------- 0: W fp32 [k][n] -> bf16 [n][k] ----------------
__global__ __launch_bounds__(256) void wprep_kernel(const float* __restrict__ W,
                                                    unsigned short* __restrict__ wbt) {
    int t = blockIdx.x * 256 + threadIdx.x;   // 8192 elements
    int k = t >> 6, nn = t & 63;
    wbt[nn * IN_CH + k] = f2b(W[t]);
}

// ---------------- 1: per-block bucket histogram (1024 thr) ----------------
__global__ __launch_bounds__(1024) void count_kernel(const int* __restrict__ col,
                                                     int* __restrict__ blkcnt,
                                                     int E, int NBLK, int NB) {
    __shared__ int h[MAX_NB];
    int tid = threadIdx.x;
    for (int i = tid; i < NB; i += 1024) h[i] = 0;
    __syncthreads();
    int e0 = blockIdx.x * CH_EDGES;
    #pragma unroll
    for (int r = 0; r < CH_EDGES / 1024; ++r) {
        int e = e0 + r * 1024 + tid;
        if (e < E) atomicAdd(&h[col[e] >> BSHIFT], 1);
    }
    __syncthreads();
    for (int i = tid; i < NB; i += 1024) blkcnt[i * NBLK + blockIdx.x] = h[i];
}

// ---------------- 2-4: multi-block exclusive scan (1024-elem blocks) --------
__global__ __launch_bounds__(1024) void scan1_kernel(const int* __restrict__ v_in,
                                                     int* __restrict__ partial, int n) {
    __shared__ int s[1024];
    int tid = threadIdx.x;
    int i   = blockIdx.x * 1024 + tid;
    int v   = (i < n) ? v_in[i] : 0;
    s[tid] = v; __syncthreads();
    #pragma unroll
    for (int off = 1; off < 1024; off <<= 1) {
        int t = (tid >= off) ? s[tid - off] : 0;
        __syncthreads();
        s[tid] += t;
        __syncthreads();
    }
    if (tid == 1023) partial[blockIdx.x] = s[1023];
}

__global__ __launch_bounds__(1024) void scan2_kernel(int* __restrict__ partial, int nb) {
    __shared__ int s[1024];
    int tid = threadIdx.x;
    int v   = (tid < nb) ? partial[tid] : 0;
    s[tid] = v; __syncthreads();
    #pragma unroll
    for (int off = 1; off < 1024; off <<= 1) {
        int t = (tid >= off) ? s[tid - off] : 0;
        __syncthreads();
        s[tid] += t;
        __syncthreads();
    }
    if (tid < nb) partial[tid] = s[tid] - v;   // exclusive
}

// scan3 (in-place ok: each block reads its own 1024 before writing) + bucket_start
__global__ __launch_bounds__(1024) void scan3_kernel(const int* __restrict__ v_in,
                                                     const int* __restrict__ partial,
                                                     int* __restrict__ v_out,
                                                     int* __restrict__ bucket_start,
                                                     int n, int NBLK, int NB, int E) {
    __shared__ int s[1024];
    int tid = threadIdx.x;
    int i   = blockIdx.x * 1024 + tid;
    int v   = (i < n) ? v_in[i] : 0;
    s[tid] = v; __syncthreads();
    #pragma unroll
    for (int off = 1; off < 1024; off <<= 1) {
        int t = (tid >= off) ? s[tid - off] : 0;
        __syncthreads();
        s[tid] += t;
        __syncthreads();
    }
    if (i < n) {
        int excl = partial[blockIdx.x] + s[tid] - v;
        v_out[i] = excl;
        if (i % NBLK == 0) bucket_start[i / NBLK] = excl;
    }
    if (i == 0) bucket_start[NB] = E;
}

// ---------------- 5: place into pairs (1024 thr, no global atomics) ---------
__global__ __launch_bounds__(1024) void place_kernel(const int* __restrict__ row,
                                                     const int* __restrict__ col,
                                                     const int* __restrict__ blkoff,
                                                     int* __restrict__ pairs,
                                                     int E, int NBLK, int NB) {
    __shared__ int cur[MAX_NB];
    int tid = threadIdx.x;
    for (int i = tid; i < NB; i += 1024) cur[i] = blkoff[i * NBLK + blockIdx.x];
    __syncthreads();
    int e0 = blockIdx.x * CH_EDGES;
    #pragma unroll
    for (int r2 = 0; r2 < CH_EDGES / 1024; ++r2) {
        int e = e0 + r2 * 1024 + tid;
        if (e < E) {
            int c = col[e];
            int b = c >> BSHIFT;
            int pos = atomicAdd(&cur[b], 1);          // LDS atomic
            pairs[pos] = row[e] | ((c & (BNODES - 1)) << 17);   // n < 2^17
        }
    }
}

// ---------------- 6: per-bucket degree -> dinv ----------------
__global__ __launch_bounds__(256) void deg_kernel(
    const int* __restrict__ bucket_start, const int* __restrict__ pairs,
    float* __restrict__ dinv, int n)
{
    __shared__ int cnt[BNODES];
    int b = blockIdx.x, tid = threadIdx.x;
    if (tid < BNODES) cnt[tid] = 0;
    __syncthreads();
    int s0 = bucket_start[b], s1 = bucket_start[b + 1];
    for (int e = s0 + tid; e < s1; e += 256) atomicAdd(&cnt[pairs[e] >> 17], 1);
    __syncthreads();
    int node = (b << BSHIFT) + tid;
    if (tid < BNODES && node < n) dinv[node] = rsqrtf((float)(cnt[tid] + 1));  // +1 self
}

// ---------------- 7: MFMA GEMM  hp_bf16 = (dinv*x) @ W ----------------
// 256 thr = 4 waves; 64-row tile; wave w does rows w*16..w*16+15 x all 64 cols.
__global__ __launch_bounds__(256) void gemm_kernel(
    const float* __restrict__ x, const unsigned short* __restrict__ wbt,
    const float* __restrict__ dinv, unsigned short* __restrict__ hpb, int n)
{
    __shared__ __align__(16) unsigned short xl[64 * XSTR];  // 17408 B
    __shared__ __align__(16) unsigned short wl[64 * XSTR];  // W^T: [n][k]

    int tid  = threadIdx.x;
    int row0 = blockIdx.x * 64;

    {
        const uint4* src = (const uint4*)wbt;
        #pragma unroll
        for (int i = 0; i < 4; ++i) {
            int flat = tid + i * 256;
            int nn = flat >> 4, c = flat & 15;
            *(uint4*)(wl + nn * XSTR + c * 8) = src[flat];
        }
    }
    #pragma unroll
    for (int i = 0; i < 4; ++i) {
        int r  = (tid >> 4) + i * 16;
        int c  = tid & 15;
        int gr = row0 + r;
        float4 v0 = make_float4(0.f,0.f,0.f,0.f), v1 = v0;
        float d = 0.f;
        if (gr < n) {
            d = dinv[gr];
            const float4* xr = (const float4*)(x + (size_t)gr * IN_CH);
            v0 = xr[c * 2]; v1 = xr[c * 2 + 1];
        }
        uint4 p;
        p.x = ((unsigned)f2b(v0.y * d) << 16) | f2b(v0.x * d);
        p.y = ((unsigned)f2b(v0.w * d) << 16) | f2b(v0.z * d);
        p.z = ((unsigned)f2b(v1.y * d) << 16) | f2b(v1.x * d);
        p.w = ((unsigned)f2b(v1.w * d) << 16) | f2b(v1.z * d);
        *(uint4*)(xl + r * XSTR + c * 8) = p;
    }
    __syncthreads();

    int lane = tid & 63, w = tid >> 6;
    int mrow = lane & 15;
    int g    = lane >> 4;

    f32x4 acc0 = {0,0,0,0}, acc1 = {0,0,0,0}, acc2 = {0,0,0,0}, acc3 = {0,0,0,0};
    const unsigned short* xbase = xl + (w * 16 + mrow) * XSTR + g * 8;
    const unsigned short* wbase = wl + mrow * XSTR + g * 8;

    #pragma unroll
    for (int k4 = 0; k4 < 4; ++k4) {
        bf16x8 a  = *(const bf16x8*)(xbase + k4 * 32);
        bf16x8 b0 = *(const bf16x8*)(wbase +             k4 * 32);
        bf16x8 b1 = *(const bf16x8*)(wbase + 16 * XSTR + k4 * 32);
        bf16x8 b2 = *(const bf16x8*)(wbase + 32 * XSTR + k4 * 32);
        bf16x8 b3 = *(const bf16x8*)(wbase + 48 * XSTR + k4 * 32);
        acc0 = __builtin_amdgcn_mfma_f32_16x16x32_bf16(a, b0, acc0, 0, 0, 0);
        acc1 = __builtin_amdgcn_mfma_f32_16x16x32_bf16(a, b1, acc1, 0, 0, 0);
        acc2 = __builtin_amdgcn_mfma_f32_16x16x32_bf16(a, b2, acc2, 0, 0, 0);
        acc3 = __builtin_amdgcn_mfma_f32_16x16x32_bf16(a, b3, acc3, 0, 0, 0);
    }
    __syncthreads();   // done reading xl; reuse it for the C tile

    {
        int cm = g * 4;
        #pragma unroll
        for (int r = 0; r < 4; ++r) {
            unsigned short* crow = xl + (w * 16 + cm + r) * XSTR + mrow;
            crow[ 0] = f2b(acc0[r]);
            crow[16] = f2b(acc1[r]);
            crow[32] = f2b(acc2[r]);
            crow[48] = f2b(acc3[r]);
        }
    }
    __syncthreads();
    #pragma unroll
    for (int i = 0; i < 2; ++i) {
        int flat = tid + i * 256;
        int r = flat >> 3, c = flat & 7;
        int gr = row0 + r;
        if (gr < n) {
            uint4 v = *(const uint4*)(xl + r * XSTR + c * 8);
            *(uint4*)(hpb + (size_t)gr * OUT_CH + c * 8) = v;
        }
    }
}

// ---------------- 8: bucket aggregation via LDS f32 atomics ----------------
// acc[col][slot]: slot s<32 holds ch 2s (lo of uint s), slot 32+s holds ch 2s+1.
// ds_add bank = slot&31 -> each half-wave covers banks 0..31 once (2-way = free).
__global__ __launch_bounds__(256) void bucket_agg_kernel(
    const int* __restrict__ bucket_start, const int* __restrict__ pairs,
    const unsigned short* __restrict__ hpb, const float* __restrict__ dinv,
    const float* __restrict__ bias, float* __restrict__ out, int n)
{
    __shared__ float acc[BNODES * 64];   // 16 KB

    int b = blockIdx.x, tid = threadIdx.x;
    int node0 = b << BSHIFT;
    int s0 = bucket_start[b], s1 = bucket_start[b + 1];

    #pragma unroll
    for (int i = 0; i < 4; ++i)
        *(float4*)&acc[tid * 4 + i * 1024] = make_float4(0.f, 0.f, 0.f, 0.f);
    __syncthreads();

    int lane = tid & 63, w = tid >> 6;
    int half = lane >> 5;      // which edge of the pair
    int hl   = lane & 31;      // uint index within hp row
    const unsigned int* hp32 = (const unsigned int*)hpb;

    // wave w handles 64-edge chunks w, w+4, w+8, ...
    for (int base = s0 + w * 64; base < s1; base += 256) {
        int cnt = min(64, s1 - base);
        int p = (base + lane < s1) ? pairs[base + lane] : 0;
        int j = 0;
        for (; j + 8 <= cnt; j += 8) {      // 8 edges: 4 loads in flight
            int p0 = __shfl(p, j     + half);
            int p1 = __shfl(p, j + 2 + half);
            int p2 = __shfl(p, j + 4 + half);
            int p3 = __shfl(p, j + 6 + half);
            unsigned v0 = hp32[(p0 & 0x1FFFF) * 32 + hl];
            unsigned v1 = hp32[(p1 & 0x1FFFF) * 32 + hl];
            unsigned v2 = hp32[(p2 & 0x1FFFF) * 32 + hl];
            unsigned v3 = hp32[(p3 & 0x1FFFF) * 32 + hl];
            float* a0 = &acc[(p0 >> 17) * 64 + hl];
            float* a1 = &acc[(p1 >> 17) * 64 + hl];
            float* a2 = &acc[(p2 >> 17) * 64 + hl];
            float* a3 = &acc[(p3 >> 17) * 64 + hl];
            lds_add(a0,      __uint_as_float(v0 << 16));
            lds_add(a0 + 32, __uint_as_float(v0 & 0xFFFF0000u));
            lds_add(a1,      __uint_as_float(v1 << 16));
            lds_add(a1 + 32, __uint_as_float(v1 & 0xFFFF0000u));
            lds_add(a2,      __uint_as_float(v2 << 16));
            lds_add(a2 + 32, __uint_as_float(v2 & 0xFFFF0000u));
            lds_add(a3,      __uint_as_float(v3 << 16));
            lds_add(a3 + 32, __uint_as_float(v3 & 0xFFFF0000u));
        }
        for (; j < cnt; j += 2) {           // tail: up to 2 edges
            int e  = j + half;
            int pe = __shfl(p, (e < cnt) ? e : j);
            unsigned v = (e < cnt) ? hp32[(pe & 0x1FFFF) * 32 + hl] : 0u;
            float* a = &acc[(pe >> 17) * 64 + hl];
            lds_add(a,      __uint_as_float(v << 16));
            lds_add(a + 32, __uint_as_float(v & 0xFFFF0000u));
        }
    }
    __syncthreads();

    // epilogue: out[node] = dinv[node] * (acc + hp[node]) + bias
    int c4 = tid & 15;           // float4 group: channels 4c4..4c4+3
    int i0 = tid >> 4;
    const uint2* hp64 = (const uint2*)hpb;
    #pragma unroll
    for (int ii = 0; ii < BNODES / 16; ++ii) {
        int i    = ii * 16 + i0;
        int node = node0 + i;
        if (node < n) {
            float2 fa = *(float2*)&acc[i * 64 + 2 * c4];        // slots 2c4,2c4+1
            float2 fb = *(float2*)&acc[i * 64 + 32 + 2 * c4];   // slots 32+2c4,+1
            float  d  = dinv[node];
            uint2  sv = hp64[node * 16 + c4];                   // self row (has dinv)
            float4 bb = ((const float4*)bias)[c4];
            float4 o;
            o.x = fmaf(d, fa.x + __uint_as_float(sv.x << 16),          bb.x);
            o.y = fmaf(d, fb.x + __uint_as_float(sv.x & 0xFFFF0000u),  bb.y);
            o.z = fmaf(d, fa.y + __uint_as_float(sv.y << 16),          bb.z);
            o.w = fmaf(d, fb.y + __uint_as_float(sv.y & 0xFFFF0000u),  bb.w);
            *(float4*)(out + (size_t)node * OUT_CH + c4 * 4) = o;
        }
    }
}

extern "C" void kernel_launch(void* const* d_in, const int* in_sizes, int n_in,
                              void* d_out, int out_size, void* d_ws, size_t ws_size,
                              hipStream_t stream) {
    const float* x  = (const float*)d_in[0];
    const int*   ei = (const int*)d_in[1];
    const float* W  = (const float*)d_in[2];
    const float* b  = (const float*)d_in[3];
    float*       out = (float*)d_out;

    int n = in_sizes[0] / IN_CH;     // 100000
    int E = in_sizes[1] / 2;         // 1600000
    const int* row = ei;
    const int* col = ei + E;

    int NB   = (n + BNODES - 1) >> BSHIFT;           // 1563
    int NBLK = (E + CH_EDGES - 1) / CH_EDGES;        // 224
    int TOT  = NB * NBLK;                            // 350112
    int nbs  = (TOT + 1023) / 1024;                  // 342 (<=1024)

    // workspace layout (blkcnt scanned in place -> doubles as blkoff)
    char* ws = (char*)d_ws;
    int*   blkcnt       = (int*)ws;   ws += (size_t)TOT * 4;
    int*   partial      = (int*)ws;   ws += 1024 * 4;
    int*   bucket_start = (int*)ws;   ws += (size_t)(NB + 1) * 4;
    float* dinv         = (float*)ws; ws += (size_t)n * 4;
    unsigned short* wbt = (unsigned short*)ws; ws += (size_t)IN_CH * OUT_CH * 2;
    ws = (char*)(((uintptr_t)ws + 255) & ~(uintptr_t)255);
    int*   pairs        = (int*)ws;   ws += (size_t)E * 4;
    ws = (char*)(((uintptr_t)ws + 255) & ~(uintptr_t)255);
    unsigned short* hpb = (unsigned short*)ws;     // n*64 bf16

    wprep_kernel     <<<(IN_CH * OUT_CH) / 256, 256, 0, stream>>>(W, wbt);
    count_kernel     <<<NBLK, 1024, 0, stream>>>(col, blkcnt, E, NBLK, NB);
    scan1_kernel     <<<nbs, 1024, 0, stream>>>(blkcnt, partial, TOT);
    scan2_kernel     <<<1, 1024, 0, stream>>>(partial, nbs);
    scan3_kernel     <<<nbs, 1024, 0, stream>>>(blkcnt, partial, blkcnt, bucket_start,
                                                TOT, NBLK, NB, E);
    place_kernel     <<<NBLK, 1024, 0, stream>>>(row, col, blkcnt, pairs, E, NBLK, NB);
    deg_kernel       <<<NB, 256, 0, stream>>>(bucket_start, pairs, dinv, n);
    gemm_kernel      <<<(n + 63) / 64, 256, 0, stream>>>(x, wbt, dinv, hpb, n);
    bucket_agg_kernel<<<NB, 256, 0, stream>>>(bucket_start, pairs, hpb, dinv, b, out, n);
}

// Round 2
// 181.232 us; speedup vs baseline: 4.1517x; 4.1517x over previous
//
#include <hip/hip_runtime.h>
#include <hip/hip_bf16.h>

// GCNConv: out = D^-1/2 (A+I) D^-1/2 (X W) + b
// N=100000, E=1600000, IN=128, OUT=64. edge_index int32, [row(E) | col(E)].
//
// Pipeline v10 — v8.1 structure, latency-optimized aggregate, slim preprocessing:
//   0. wprep:       W fp32 [k][n] -> wbt bf16 [n][k]; also zeroes bucket_cnt
//   1. count:       1024-thr blocks, LDS histogram -> atomicAdd bucket_cnt[NB]
//   2. scanB:       ONE block scans 782 bucket counts -> bucket_start + cursor
//   3. place:       LDS histogram -> block reserves span via atomicAdd(cursor),
//                   then LDS-cursor scatter. (replaces blkcnt matrix + 3 scans;
//                   intra-bucket order nondeterministic — harmless, fp32 accum)
//   4. bucket_sort: in-LDS counting sort per 128-node bucket -> csr_row,
//                   row_start, dinv
//   5. gemm:        MFMA 16x16x32 bf16; hp_bf16 = (dinv[row]*x) @ W
//   6. aggregate:   wave per node; fully-predicated 16-edge blocks, 8 gathers
//                   in flight, NO serial tail (v8.1 tail was up to 4 dependent
//                   gather rounds = the latency bottleneck).

#define IN_CH 128
#define OUT_CH 64
#define BSHIFT 7            // 128 nodes per bucket
#define BNODES 128
#define MAX_NB 800
#define CH_EDGES 7168       // edges per partition block (7 rounds x 1024 thr)
#define SORT_CAP 4096       // LDS sort capacity (avg bucket = 2046 edges)
#define XSTR 136            // bf16 LDS row stride: 272B = 17x16B -> conflict-free b128

typedef short bf16x8 __attribute__((ext_vector_type(8)));
typedef float f32x4  __attribute__((ext_vector_type(4)));

__device__ __forceinline__ unsigned short f2b(float f) {   // RNE fp32->bf16
    unsigned int u = __float_as_uint(f);
    return (unsigned short)((u + 0x7FFFu + ((u >> 16) & 1u)) >> 16);
}

// ---------------- 0: W fp32 [k][n] -> bf16 [n][k]; zero bucket_cnt ----------
__global__ __launch_bounds__(256) void wprep_kernel(const float* __restrict__ W,
                                                    unsigned short* __restrict__ wbt,
                                                    int* __restrict__ bucket_cnt,
                                                    int NB) {
    int t = blockIdx.x * 256 + threadIdx.x;   // 8192 threads
    int k = t >> 6, nn = t & 63;
    wbt[nn * IN_CH + k] = f2b(W[t]);
    if (t < NB) bucket_cnt[t] = 0;
}

// ---------------- 1: per-block bucket histogram -> global counts ------------
__global__ __launch_bounds__(1024) void count_kernel(const int* __restrict__ col,
                                                     int* __restrict__ bucket_cnt,
                                                     int E, int NB) {
    __shared__ int h[MAX_NB];
    int tid = threadIdx.x;
    for (int i = tid; i < NB; i += 1024) h[i] = 0;
    __syncthreads();
    int e0 = blockIdx.x * CH_EDGES;
    #pragma unroll
    for (int r = 0; r < CH_EDGES / 1024; ++r) {
        int e = e0 + r * 1024 + tid;
        if (e < E) atomicAdd(&h[col[e] >> BSHIFT], 1);
    }
    __syncthreads();
    for (int i = tid; i < NB; i += 1024)
        if (h[i]) atomicAdd(&bucket_cnt[i], h[i]);
}

// ---------------- 2: single-block scan over NB buckets ----------------
// NB = 782 <= 1024. bucket_start = exclusive scan; cursor = same (mutable copy).
__global__ __launch_bounds__(1024) void scanB_kernel(const int* __restrict__ bucket_cnt,
                                                     int* __restrict__ bucket_start,
                                                     int* __restrict__ cursor,
                                                     int NB, int E) {
    __shared__ int s[1024];
    int tid = threadIdx.x;
    int v   = (tid < NB) ? bucket_cnt[tid] : 0;
    s[tid] = v; __syncthreads();
    #pragma unroll
    for (int off = 1; off < 1024; off <<= 1) {
        int t = (tid >= off) ? s[tid - off] : 0;
        __syncthreads();
        s[tid] += t;
        __syncthreads();
    }
    if (tid < NB) {
        int excl = s[tid] - v;
        bucket_start[tid] = excl;
        cursor[tid] = excl;
    }
    if (tid == 0) bucket_start[NB] = E;
}

// ---------------- 3: place into pairs (LDS hist + block reservation) --------
__global__ __launch_bounds__(1024) void place_kernel(const int* __restrict__ row,
                                                     const int* __restrict__ col,
                                                     int* __restrict__ cursor,
                                                     int* __restrict__ pairs,
                                                     int E, int NB) {
    __shared__ int h[MAX_NB];
    int tid = threadIdx.x;
    for (int i = tid; i < NB; i += 1024) h[i] = 0;
    __syncthreads();
    int e0 = blockIdx.x * CH_EDGES;
    #pragma unroll
    for (int r1 = 0; r1 < CH_EDGES / 1024; ++r1) {
        int e = e0 + r1 * 1024 + tid;
        if (e < E) atomicAdd(&h[col[e] >> BSHIFT], 1);
    }
    __syncthreads();
    // reserve a contiguous span per (bucket, block); h[i] becomes local cursor
    for (int i = tid; i < NB; i += 1024) {
        int c = h[i];
        if (c) h[i] = atomicAdd(&cursor[i], c);
    }
    __syncthreads();
    #pragma unroll
    for (int r2 = 0; r2 < CH_EDGES / 1024; ++r2) {
        int e = e0 + r2 * 1024 + tid;
        if (e < E) {
            int c = col[e];
            int b = c >> BSHIFT;
            int pos = atomicAdd(&h[b], 1);            // LDS atomic
            pairs[pos] = row[e] | ((c & (BNODES - 1)) << 17);   // n < 2^17
        }
    }
}

// ---------------- 4: per-bucket in-LDS counting sort ----------------
__global__ __launch_bounds__(256) void bucket_sort_kernel(
    const int* __restrict__ bucket_start, const int* __restrict__ pairs,
    int* __restrict__ csr_row, int* __restrict__ row_start,
    float* __restrict__ dinv, int n, int E)
{
    __shared__ int cnt[BNODES];      // counts -> inclusive scan
    __shared__ int deg[BNODES];
    __shared__ int cur[BNODES];
    __shared__ int sorted[SORT_CAP];

    int b = blockIdx.x, tid = threadIdx.x;
    int node0 = b << BSHIFT;
    int nodeCnt = min(BNODES, n - node0);
    int s0 = bucket_start[b], s1 = bucket_start[b + 1];
    int m = s1 - s0;

    if (tid < BNODES) cnt[tid] = 0;
    __syncthreads();
    for (int e = s0 + tid; e < s1; e += 256) atomicAdd(&cnt[pairs[e] >> 17], 1);
    __syncthreads();
    if (tid < BNODES) deg[tid] = cnt[tid];
    __syncthreads();
    #pragma unroll
    for (int off = 1; off < BNODES; off <<= 1) {      // inclusive scan over 128
        int t = (tid >= off && tid < BNODES) ? cnt[tid - off] : 0;
        __syncthreads();
        if (tid < BNODES) cnt[tid] += t;
        __syncthreads();
    }
    if (tid < BNODES) {
        int excl = cnt[tid] - deg[tid];
        cur[tid] = excl;
        if (tid < nodeCnt) {
            row_start[node0 + tid] = s0 + excl;
            dinv[node0 + tid] = rsqrtf((float)(deg[tid] + 1));   // +1 self loop
        }
    }
    if (b == gridDim.x - 1 && tid == 0) row_start[n] = E;
    __syncthreads();

    if (m <= SORT_CAP) {
        for (int e = s0 + tid; e < s1; e += 256) {
            int p   = pairs[e];
            int pos = atomicAdd(&cur[p >> 17], 1);
            sorted[pos] = p & 0x1FFFF;
        }
        __syncthreads();
        for (int i = tid; i < m; i += 256) csr_row[s0 + i] = sorted[i];
    } else {   // fallback: direct global scatter (statistically unreachable)
        if (tid < BNODES) cur[tid] += s0;
        __syncthreads();
        for (int e = s0 + tid; e < s1; e += 256) {
            int p   = pairs[e];
            int pos = atomicAdd(&cur[p >> 17], 1);
            csr_row[pos] = p & 0x1FFFF;
        }
    }
}

// ---------------- 5: MFMA GEMM  hp_bf16 = (dinv*x) @ W ----------------
// 256 thr = 4 waves; 64-row tile; wave w does rows w*16..w*16+15 x all 64 cols.
__global__ __launch_bounds__(256) void gemm_kernel(
    const float* __restrict__ x, const unsigned short* __restrict__ wbt,
    const float* __restrict__ dinv, unsigned short* __restrict__ hpb, int n)
{
    __shared__ __align__(16) unsigned short xl[64 * XSTR];  // 17408 B
    __shared__ __align__(16) unsigned short wl[64 * XSTR];  // W^T: [n][k]

    int tid  = threadIdx.x;
    int row0 = blockIdx.x * 64;

    {
        const uint4* src = (const uint4*)wbt;
        #pragma unroll
        for (int i = 0; i < 4; ++i) {
            int flat = tid + i * 256;
            int nn = flat >> 4, c = flat & 15;
            *(uint4*)(wl + nn * XSTR + c * 8) = src[flat];
        }
    }
    #pragma unroll
    for (int i = 0; i < 4; ++i) {
        int r  = (tid >> 4) + i * 16;
        int c  = tid & 15;
        int gr = row0 + r;
        float4 v0 = make_float4(0.f,0.f,0.f,0.f), v1 = v0;
        float d = 0.f;
        if (gr < n) {
            d = dinv[gr];
            const float4* xr = (const float4*)(x + (size_t)gr * IN_CH);
            v0 = xr[c * 2]; v1 = xr[c * 2 + 1];
        }
        uint4 p;
        p.x = ((unsigned)f2b(v0.y * d) << 16) | f2b(v0.x * d);
        p.y = ((unsigned)f2b(v0.w * d) << 16) | f2b(v0.z * d);
        p.z = ((unsigned)f2b(v1.y * d) << 16) | f2b(v1.x * d);
        p.w = ((unsigned)f2b(v1.w * d) << 16) | f2b(v1.z * d);
        *(uint4*)(xl + r * XSTR + c * 8) = p;
    }
    __syncthreads();

    int lane = tid & 63, w = tid >> 6;
    int mrow = lane & 15;
    int g    = lane >> 4;

    f32x4 acc0 = {0,0,0,0}, acc1 = {0,0,0,0}, acc2 = {0,0,0,0}, acc3 = {0,0,0,0};
    const unsigned short* xbase = xl + (w * 16 + mrow) * XSTR + g * 8;
    const unsigned short* wbase = wl + mrow * XSTR + g * 8;

    #pragma unroll
    for (int k4 = 0; k4 < 4; ++k4) {
        bf16x8 a  = *(const bf16x8*)(xbase + k4 * 32);
        bf16x8 b0 = *(const bf16x8*)(wbase +             k4 * 32);
        bf16x8 b1 = *(const bf16x8*)(wbase + 16 * XSTR + k4 * 32);
        bf16x8 b2 = *(const bf16x8*)(wbase + 32 * XSTR + k4 * 32);
        bf16x8 b3 = *(const bf16x8*)(wbase + 48 * XSTR + k4 * 32);
        acc0 = __builtin_amdgcn_mfma_f32_16x16x32_bf16(a, b0, acc0, 0, 0, 0);
        acc1 = __builtin_amdgcn_mfma_f32_16x16x32_bf16(a, b1, acc1, 0, 0, 0);
        acc2 = __builtin_amdgcn_mfma_f32_16x16x32_bf16(a, b2, acc2, 0, 0, 0);
        acc3 = __builtin_amdgcn_mfma_f32_16x16x32_bf16(a, b3, acc3, 0, 0, 0);
    }
    __syncthreads();   // done reading xl; reuse it for the C tile

    {
        int cm = g * 4;
        #pragma unroll
        for (int r = 0; r < 4; ++r) {
            unsigned short* crow = xl + (w * 16 + cm + r) * XSTR + mrow;
            crow[ 0] = f2b(acc0[r]);
            crow[16] = f2b(acc1[r]);
            crow[32] = f2b(acc2[r]);
            crow[48] = f2b(acc3[r]);
        }
    }
    __syncthreads();
    #pragma unroll
    for (int i = 0; i < 2; ++i) {
        int flat = tid + i * 256;
        int r = flat >> 3, c = flat & 7;
        int gr = row0 + r;
        if (gr < n) {
            uint4 v = *(const uint4*)(xl + r * XSTR + c * 8);
            *(uint4*)(hpb + (size_t)gr * OUT_CH + c * 8) = v;
        }
    }
}

// ---------------- 6: aggregate — fully predicated 16-edge blocks ------------
// Wave per node. 8 gathers in flight per lane (16 edges via half-waves); no
// serial tail: lanes beyond cnt are predicated off (v=0). Latency chain per
// wave: row_start -> csr_row -> shfl -> ONE gather round.
__global__ __launch_bounds__(256) void aggregate_kernel(
    const int* __restrict__ row_start, const int* __restrict__ csr_row,
    const unsigned short* __restrict__ hpb, const float* __restrict__ dinv,
    const float* __restrict__ bias, float* __restrict__ out, int n)
{
    int wid  = (blockIdx.x * 256 + threadIdx.x) >> 6;   // node id
    int lane = threadIdx.x & 63;
    if (wid >= n) return;
    int half = lane >> 5;      // which edge of the pair
    int hl   = lane & 31;      // channel-pair index

    const unsigned int* hp32 = (const unsigned int*)hpb;   // row stride 32 uints

    int s0 = row_start[wid];
    int s1 = row_start[wid + 1];

    float al0=0.f,al1=0.f,al2=0.f,al3=0.f,al4=0.f,al5=0.f,al6=0.f,al7=0.f;
    float ah0=0.f,ah1=0.f,ah2=0.f,ah3=0.f,ah4=0.f,ah5=0.f,ah6=0.f,ah7=0.f;

    for (int base = s0; base < s1; base += 64) {
        int cnt  = min(64, s1 - base);
        int ridx = (base + lane < s1) ? csr_row[base + lane] : 0;
        for (int j0 = 0; j0 < cnt; j0 += 16) {
            int e0 = j0      + half, e1 = j0 +  2 + half;
            int e2 = j0 +  4 + half, e3 = j0 +  6 + half;
            int e4 = j0 +  8 + half, e5 = j0 + 10 + half;
            int e6 = j0 + 12 + half, e7 = j0 + 14 + half;
            int r0 = __shfl(ridx, e0), r1 = __shfl(ridx, e1);
            int r2 = __shfl(ridx, e2), r3 = __shfl(ridx, e3);
            int r4 = __shfl(ridx, e4), r5 = __shfl(ridx, e5);
            int r6 = __shfl(ridx, e6), r7 = __shfl(ridx, e7);
            unsigned v0 = (e0 < cnt) ? hp32[(size_t)r0 * 32 + hl] : 0u;
            unsigned v1 = (e1 < cnt) ? hp32[(size_t)r1 * 32 + hl] : 0u;
            unsigned v2 = (e2 < cnt) ? hp32[(size_t)r2 * 32 + hl] : 0u;
            unsigned v3 = (e3 < cnt) ? hp32[(size_t)r3 * 32 + hl] : 0u;
            unsigned v4 = (e4 < cnt) ? hp32[(size_t)r4 * 32 + hl] : 0u;
            unsigned v5 = (e5 < cnt) ? hp32[(size_t)r5 * 32 + hl] : 0u;
            unsigned v6 = (e6 < cnt) ? hp32[(size_t)r6 * 32 + hl] : 0u;
            unsigned v7 = (e7 < cnt) ? hp32[(size_t)r7 * 32 + hl] : 0u;
            al0 += __uint_as_float(v0 << 16); ah0 += __uint_as_float(v0 & 0xFFFF0000u);
            al1 += __uint_as_float(v1 << 16); ah1 += __uint_as_float(v1 & 0xFFFF0000u);
            al2 += __uint_as_float(v2 << 16); ah2 += __uint_as_float(v2 & 0xFFFF0000u);
            al3 += __uint_as_float(v3 << 16); ah3 += __uint_as_float(v3 & 0xFFFF0000u);
            al4 += __uint_as_float(v4 << 16); ah4 += __uint_as_float(v4 & 0xFFFF0000u);
            al5 += __uint_as_float(v5 << 16); ah5 += __uint_as_float(v5 & 0xFFFF0000u);
            al6 += __uint_as_float(v6 << 16); ah6 += __uint_as_float(v6 & 0xFFFF0000u);
            al7 += __uint_as_float(v7 << 16); ah7 += __uint_as_float(v7 & 0xFFFF0000u);
        }
    }
    float sl = ((al0 + al1) + (al2 + al3)) + ((al4 + al5) + (al6 + al7));
    float sh = ((ah0 + ah1) + (ah2 + ah3)) + ((ah4 + ah5) + (ah6 + ah7));
    sl += __shfl_xor(sl, 32);
    sh += __shfl_xor(sh, 32);

    if (half == 0) {
        unsigned int sv = hp32[(size_t)wid * 32 + hl];   // self loop
        sl += __uint_as_float(sv << 16);
        sh += __uint_as_float(sv & 0xFFFF0000u);
        float d = dinv[wid];
        float2 bb = ((const float2*)bias)[hl];
        float2 o;
        o.x = fmaf(d, sl, bb.x);
        o.y = fmaf(d, sh, bb.y);
        ((float2*)(out + (size_t)wid * OUT_CH))[hl] = o;
    }
}

extern "C" void kernel_launch(void* const* d_in, const int* in_sizes, int n_in,
                              void* d_out, int out_size, void* d_ws, size_t ws_size,
                              hipStream_t stream) {
    const float* x  = (const float*)d_in[0];
    const int*   ei = (const int*)d_in[1];
    const float* W  = (const float*)d_in[2];
    const float* b  = (const float*)d_in[3];
    float*       out = (float*)d_out;

    int n = in_sizes[0] / IN_CH;     // 100000
    int E = in_sizes[1] / 2;         // 1600000
    const int* row = ei;
    const int* col = ei + E;

    int NB   = (n + BNODES - 1) >> BSHIFT;           // 782 (<= 1024 for scanB)
    int NBLK = (E + CH_EDGES - 1) / CH_EDGES;        // 224

    // workspace layout; hpb (bf16, n*64) overlays pairs (dead after bucket_sort)
    char* ws = (char*)d_ws;
    int*   bucket_cnt   = (int*)ws;   ws += (size_t)NB * 4;
    int*   bucket_start = (int*)ws;   ws += (size_t)(NB + 1) * 4;
    int*   cursor       = (int*)ws;   ws += (size_t)NB * 4;
    int*   row_start    = (int*)ws;   ws += (size_t)(n + 1) * 4;
    float* dinv         = (float*)ws; ws += (size_t)n * 4;
    int*   csr_row      = (int*)ws;   ws += (size_t)E * 4;
    unsigned short* wbt = (unsigned short*)ws; ws += (size_t)IN_CH * OUT_CH * 2;
    ws = (char*)(((uintptr_t)ws + 255) & ~(uintptr_t)255);
    int*            pairs = (int*)ws;              // E ints        (phase 1)
    unsigned short* hpb   = (unsigned short*)ws;   // n*64 bf16     (phase 2)

    wprep_kernel      <<<(IN_CH * OUT_CH) / 256, 256, 0, stream>>>(W, wbt, bucket_cnt, NB);
    count_kernel      <<<NBLK, 1024, 0, stream>>>(col, bucket_cnt, E, NB);
    scanB_kernel      <<<1, 1024, 0, stream>>>(bucket_cnt, bucket_start, cursor, NB, E);
    place_kernel      <<<NBLK, 1024, 0, stream>>>(row, col, cursor, pairs, E, NB);
    bucket_sort_kernel<<<NB, 256, 0, stream>>>(bucket_start, pairs, csr_row, row_start, dinv, n, E);
    gemm_kernel       <<<(n + 63) / 64, 256, 0, stream>>>(x, wbt, dinv, hpb, n);
    aggregate_kernel  <<<(n + 3) / 4, 256, 0, stream>>>(row_start, csr_row, hpb, dinv, b, out, n);
}

// Round 3
// 174.242 us; speedup vs baseline: 4.3182x; 1.0401x over previous
//
#include <hip/hip_runtime.h>
#include <hip/hip_bf16.h>

// GCNConv: out = D^-1/2 (A+I) D^-1/2 (X W) + b
// N=100000, E=1600000, IN=128, OUT=64. edge_index int32, [row(E) | col(E)].
//
// Pipeline v11 — fixed-stride buckets + padded sentinel CSR:
//   0. wprep:       W fp32 [k][n] -> wbt bf16 [n][k]; cursor[b] = b*PSTRIDE
//   1. place:       LDS hist -> span reservation via atomicAdd(cursor) ->
//                   scatter pairs at fixed per-bucket stride (count/scan GONE)
//   2. bucket_sort: in-LDS counting sort, per-node segments PADDED to x8 with
//                   sentinel row n; row_info = start(22b) | rounds(9b); dinv
//   3. gemm:        MFMA 16x16x32 bf16; hp_bf16 = (dinv*x) @ W; row n = zeros
//   4. aggregate:   wave per node; uniform round count, NO bounds checks, NO
//                   shfl/bpermute (broadcast csr loads), 32-bit voffset gathers.
//                   Sentinel gathers all hit one L1-resident line (~free).

#define IN_CH 128
#define OUT_CH 64
#define BSHIFT 7            // 128 nodes per bucket
#define BNODES 128
#define MAX_NB 800
#define CH_EDGES 7168       // edges per partition block (7 rounds x 1024 thr)
#define SORT_CAP 4096       // LDS sort capacity (padded bucket <= ~3300)
#define PSTRIDE 4096        // ints per bucket in pairs AND csr (fixed stride)
#define XSTR 136            // bf16 LDS row stride: 272B -> conflict-free b128

typedef short bf16x8 __attribute__((ext_vector_type(8)));
typedef float f32x4  __attribute__((ext_vector_type(4)));

__device__ __forceinline__ unsigned short f2b(float f) {   // RNE fp32->bf16
    unsigned int u = __float_as_uint(f);
    return (unsigned short)((u + 0x7FFFu + ((u >> 16) & 1u)) >> 16);
}

// ---------------- 0: W fp32 [k][n] -> bf16 [n][k]; init cursors ----------
__global__ __launch_bounds__(256) void wprep_kernel(const float* __restrict__ W,
                                                    unsigned short* __restrict__ wbt,
                                                    int* __restrict__ cursor,
                                                    int NB) {
    int t = blockIdx.x * 256 + threadIdx.x;   // 8192 threads
    int k = t >> 6, nn = t & 63;
    wbt[nn * IN_CH + k] = f2b(W[t]);
    if (t < NB) cursor[t] = t * PSTRIDE;
}

// ---------------- 1: place into pairs (LDS hist + span reservation) --------
__global__ __launch_bounds__(1024) void place_kernel(const int* __restrict__ row,
                                                     const int* __restrict__ col,
                                                     int* __restrict__ cursor,
                                                     int* __restrict__ pairs,
                                                     int E, int NB) {
    __shared__ int h[MAX_NB];
    int tid = threadIdx.x;
    for (int i = tid; i < NB; i += 1024) h[i] = 0;
    __syncthreads();
    int e0 = blockIdx.x * CH_EDGES;
    #pragma unroll
    for (int r1 = 0; r1 < CH_EDGES / 1024; ++r1) {
        int e = e0 + r1 * 1024 + tid;
        if (e < E) atomicAdd(&h[col[e] >> BSHIFT], 1);
    }
    __syncthreads();
    // reserve a contiguous span per (bucket, block); h[i] becomes local cursor
    for (int i = tid; i < NB; i += 1024) {
        int c = h[i];
        if (c) h[i] = atomicAdd(&cursor[i], c);
    }
    __syncthreads();
    #pragma unroll
    for (int r2 = 0; r2 < CH_EDGES / 1024; ++r2) {
        int e = e0 + r2 * 1024 + tid;
        if (e < E) {
            int c = col[e];
            int b = c >> BSHIFT;
            int pos = atomicAdd(&h[b], 1);            // LDS atomic
            pairs[pos] = row[e] | ((c & (BNODES - 1)) << 17);   // n < 2^17
        }
    }
}

// ---------------- 2: per-bucket in-LDS counting sort (padded, sentinel) -----
// csr segment for node = 8-aligned; pad slots hold sentinel n (zero hp row).
// row_info[node] = global_start (22b) | (padded_deg/8) << 22.
__global__ __launch_bounds__(256) void bucket_sort_kernel(
    const int* __restrict__ cursor_end, const int* __restrict__ pairs,
    int* __restrict__ csr, int* __restrict__ row_info,
    float* __restrict__ dinv, int n)
{
    __shared__ int cnt[BNODES];      // padded counts -> inclusive scan
    __shared__ int deg[BNODES];
    __shared__ int pad8[BNODES];
    __shared__ int cur[BNODES];
    __shared__ int sorted[SORT_CAP];
    __shared__ int ptot_s;

    int b = blockIdx.x, tid = threadIdx.x;
    int node0 = b << BSHIFT;
    int nodeCnt = min(BNODES, n - node0);
    int s0 = b * PSTRIDE;
    int m  = cursor_end[b] - s0;

    if (tid < BNODES) cnt[tid] = 0;
    __syncthreads();
    for (int e = tid; e < m; e += 256) atomicAdd(&cnt[pairs[s0 + e] >> 17], 1);
    __syncthreads();
    if (tid < BNODES) {
        int d  = cnt[tid];
        int p8 = (d + 7) & ~7;
        deg[tid]  = d;
        pad8[tid] = p8;
        cnt[tid]  = p8;
    }
    __syncthreads();
    #pragma unroll
    for (int off = 1; off < BNODES; off <<= 1) {      // inclusive scan over 128
        int t = (tid >= off && tid < BNODES) ? cnt[tid - off] : 0;
        __syncthreads();
        if (tid < BNODES) cnt[tid] += t;
        __syncthreads();
    }
    if (tid < BNODES) {
        int excl = cnt[tid] - pad8[tid];
        cur[tid] = excl;
        if (tid < nodeCnt) {
            row_info[node0 + tid] = (s0 + excl) | ((pad8[tid] >> 3) << 22);
            dinv[node0 + tid] = rsqrtf((float)(deg[tid] + 1));   // +1 self loop
        }
    }
    if (tid == BNODES - 1) ptot_s = cnt[tid];
    __syncthreads();
    int ptot = ptot_s;

    if (ptot <= SORT_CAP) {
        for (int i = tid; i < ptot; i += 256) sorted[i] = n;     // sentinel fill
        __syncthreads();
        for (int e = tid; e < m; e += 256) {
            int p   = pairs[s0 + e];
            int pos = atomicAdd(&cur[p >> 17], 1);
            sorted[pos] = p & 0x1FFFF;
        }
        __syncthreads();
        for (int i = tid; i < ptot; i += 256) csr[s0 + i] = sorted[i];
    } else {   // fallback: global prefill + scatter (statistically unreachable)
        for (int i = tid; i < ptot; i += 256) csr[s0 + i] = n;
        __syncthreads();   // compiler drains vmem before barrier -> WAW ordered
        for (int e = tid; e < m; e += 256) {
            int p   = pairs[s0 + e];
            int pos = atomicAdd(&cur[p >> 17], 1);
            csr[s0 + pos] = p & 0x1FFFF;
        }
    }
}

// ---------------- 3: MFMA GEMM  hp_bf16 = (dinv*x) @ W  (+ zero row n) ------
// 256 thr = 4 waves; 64-row tile; wave w does rows w*16..w*16+15 x all 64 cols.
__global__ __launch_bounds__(256) void gemm_kernel(
    const float* __restrict__ x, const unsigned short* __restrict__ wbt,
    const float* __restrict__ dinv, unsigned short* __restrict__ hpb, int n)
{
    __shared__ __align__(16) unsigned short xl[64 * XSTR];  // 17408 B
    __shared__ __align__(16) unsigned short wl[64 * XSTR];  // W^T: [n][k]

    int tid  = threadIdx.x;
    int row0 = blockIdx.x * 64;

    {
        const uint4* src = (const uint4*)wbt;
        #pragma unroll
        for (int i = 0; i < 4; ++i) {
            int flat = tid + i * 256;
            int nn = flat >> 4, c = flat & 15;
            *(uint4*)(wl + nn * XSTR + c * 8) = src[flat];
        }
    }
    #pragma unroll
    for (int i = 0; i < 4; ++i) {
        int r  = (tid >> 4) + i * 16;
        int c  = tid & 15;
        int gr = row0 + r;
        float4 v0 = make_float4(0.f,0.f,0.f,0.f), v1 = v0;
        float d = 0.f;
        if (gr < n) {
            d = dinv[gr];
            const float4* xr = (const float4*)(x + (size_t)gr * IN_CH);
            v0 = xr[c * 2]; v1 = xr[c * 2 + 1];
        }
        uint4 p;
        p.x = ((unsigned)f2b(v0.y * d) << 16) | f2b(v0.x * d);
        p.y = ((unsigned)f2b(v0.w * d) << 16) | f2b(v0.z * d);
        p.z = ((unsigned)f2b(v1.y * d) << 16) | f2b(v1.x * d);
        p.w = ((unsigned)f2b(v1.w * d) << 16) | f2b(v1.z * d);
        *(uint4*)(xl + r * XSTR + c * 8) = p;
    }
    __syncthreads();

    int lane = tid & 63, w = tid >> 6;
    int mrow = lane & 15;
    int g    = lane >> 4;

    f32x4 acc0 = {0,0,0,0}, acc1 = {0,0,0,0}, acc2 = {0,0,0,0}, acc3 = {0,0,0,0};
    const unsigned short* xbase = xl + (w * 16 + mrow) * XSTR + g * 8;
    const unsigned short* wbase = wl + mrow * XSTR + g * 8;

    #pragma unroll
    for (int k4 = 0; k4 < 4; ++k4) {
        bf16x8 a  = *(const bf16x8*)(xbase + k4 * 32);
        bf16x8 b0 = *(const bf16x8*)(wbase +             k4 * 32);
        bf16x8 b1 = *(const bf16x8*)(wbase + 16 * XSTR + k4 * 32);
        bf16x8 b2 = *(const bf16x8*)(wbase + 32 * XSTR + k4 * 32);
        bf16x8 b3 = *(const bf16x8*)(wbase + 48 * XSTR + k4 * 32);
        acc0 = __builtin_amdgcn_mfma_f32_16x16x32_bf16(a, b0, acc0, 0, 0, 0);
        acc1 = __builtin_amdgcn_mfma_f32_16x16x32_bf16(a, b1, acc1, 0, 0, 0);
        acc2 = __builtin_amdgcn_mfma_f32_16x16x32_bf16(a, b2, acc2, 0, 0, 0);
        acc3 = __builtin_amdgcn_mfma_f32_16x16x32_bf16(a, b3, acc3, 0, 0, 0);
    }
    __syncthreads();   // done reading xl; reuse it for the C tile

    {
        int cm = g * 4;
        #pragma unroll
        for (int r = 0; r < 4; ++r) {
            unsigned short* crow = xl + (w * 16 + cm + r) * XSTR + mrow;
            crow[ 0] = f2b(acc0[r]);
            crow[16] = f2b(acc1[r]);
            crow[32] = f2b(acc2[r]);
            crow[48] = f2b(acc3[r]);
        }
    }
    __syncthreads();
    #pragma unroll
    for (int i = 0; i < 2; ++i) {
        int flat = tid + i * 256;
        int r = flat >> 3, c = flat & 7;
        int gr = row0 + r;
        if (gr <= n) {     // row n = sentinel zero row for padded aggregation
            uint4 v = *(const uint4*)(xl + r * XSTR + c * 8);
            *(uint4*)(hpb + (size_t)gr * OUT_CH + c * 8) = v;
        }
    }
}

// ---------------- 4: aggregate — uniform rounds, broadcast csr, no tails ----
// Wave per node; half-waves process 2 edges at a time, 4 gathers in flight.
// Padded segments (sentinel n -> zero row, one L1-resident line): no bounds
// checks, no shfl/bpermute, no exec-mask ops in the hot loop.
__global__ __launch_bounds__(256) void aggregate_kernel(
    const int* __restrict__ row_info, const int* __restrict__ csr,
    const unsigned short* __restrict__ hpb, const float* __restrict__ dinv,
    const float* __restrict__ bias, float* __restrict__ out, int n)
{
    int wid  = (blockIdx.x * 256 + threadIdx.x) >> 6;   // node id
    int lane = threadIdx.x & 63;
    if (wid >= n) return;
    int half = lane >> 5;      // which edge of the pair
    int hl   = lane & 31;      // channel-pair index

    const unsigned int* hp32 = (const unsigned int*)hpb;   // row stride 32 uints

    int info = row_info[wid];
    int s    = info & 0x3FFFFF;
    int rnds = info >> 22;               // padded_deg / 8 (<= ~7)

    const int* ep = csr + s + half;      // broadcast reads: 2 lines per load

    float al0=0.f,ah0=0.f, al1=0.f,ah1=0.f, al2=0.f,ah2=0.f, al3=0.f,ah3=0.f;
    for (int rr = 0; rr < rnds; ++rr, ep += 8) {
        int r0 = ep[0];
        int r1 = ep[2];
        int r2 = ep[4];
        int r3 = ep[6];
        unsigned v0 = hp32[(unsigned)(r0 * 32 + hl)];
        unsigned v1 = hp32[(unsigned)(r1 * 32 + hl)];
        unsigned v2 = hp32[(unsigned)(r2 * 32 + hl)];
        unsigned v3 = hp32[(unsigned)(r3 * 32 + hl)];
        al0 += __uint_as_float(v0 << 16); ah0 += __uint_as_float(v0 & 0xFFFF0000u);
        al1 += __uint_as_float(v1 << 16); ah1 += __uint_as_float(v1 & 0xFFFF0000u);
        al2 += __uint_as_float(v2 << 16); ah2 += __uint_as_float(v2 & 0xFFFF0000u);
        al3 += __uint_as_float(v3 << 16); ah3 += __uint_as_float(v3 & 0xFFFF0000u);
    }
    float sl = (al0 + al1) + (al2 + al3);
    float sh = (ah0 + ah1) + (ah2 + ah3);
    sl += __shfl_xor(sl, 32);
    sh += __shfl_xor(sh, 32);

    if (half == 0) {
        unsigned int sv = hp32[(size_t)wid * 32 + hl];   // self loop
        sl += __uint_as_float(sv << 16);
        sh += __uint_as_float(sv & 0xFFFF0000u);
        float d = dinv[wid];
        float2 bb = ((const float2*)bias)[hl];
        float2 o;
        o.x = fmaf(d, sl, bb.x);
        o.y = fmaf(d, sh, bb.y);
        ((float2*)(out + (size_t)wid * OUT_CH))[hl] = o;
    }
}

extern "C" void kernel_launch(void* const* d_in, const int* in_sizes, int n_in,
                              void* d_out, int out_size, void* d_ws, size_t ws_size,
                              hipStream_t stream) {
    const float* x  = (const float*)d_in[0];
    const int*   ei = (const int*)d_in[1];
    const float* W  = (const float*)d_in[2];
    const float* b  = (const float*)d_in[3];
    float*       out = (float*)d_out;

    int n = in_sizes[0] / IN_CH;     // 100000
    int E = in_sizes[1] / 2;         // 1600000
    const int* row = ei;
    const int* col = ei + E;

    int NB   = (n + BNODES - 1) >> BSHIFT;           // 782
    int NBLK = (E + CH_EDGES - 1) / CH_EDGES;        // 224

    // workspace layout (ws ~= 256 MiB; total used ~40 MB, no overlays needed)
    char* ws = (char*)d_ws;
    int*   cursor       = (int*)ws;   ws += (size_t)NB * 4;
    int*   row_info     = (int*)ws;   ws += (size_t)n * 4;
    float* dinv         = (float*)ws; ws += (size_t)n * 4;
    unsigned short* wbt = (unsigned short*)ws; ws += (size_t)IN_CH * OUT_CH * 2;
    ws = (char*)(((uintptr_t)ws + 255) & ~(uintptr_t)255);
    int*   pairs        = (int*)ws;   ws += (size_t)NB * PSTRIDE * 4;   // 12.8 MB
    int*   csr          = (int*)ws;   ws += (size_t)NB * PSTRIDE * 4;   // 12.8 MB
    unsigned short* hpb = (unsigned short*)ws;   // (n+1)*64 bf16 (row n = zeros)

    wprep_kernel      <<<(IN_CH * OUT_CH) / 256, 256, 0, stream>>>(W, wbt, cursor, NB);
    place_kernel      <<<NBLK, 1024, 0, stream>>>(row, col, cursor, pairs, E, NB);
    bucket_sort_kernel<<<NB, 256, 0, stream>>>(cursor, pairs, csr, row_info, dinv, n);
    gemm_kernel       <<<(n + 63) / 64, 256, 0, stream>>>(x, wbt, dinv, hpb, n);
    aggregate_kernel  <<<(n + 3) / 4, 256, 0, stream>>>(row_info, csr, hpb, dinv, b, out, n);
}